// Round 3
// baseline (4000.491 us; speedup 1.0000x reference)
//
#include <hip/hip_runtime.h>
#include <hip/hip_bf16.h>

// Geometry (pad=1 convs!): conv1/conv2 -> (2,16,128^3), conv3 s2 -> (2,32,64^3)
// patches: Do=Ho=Wo=7, M=686, pdim=131072. Out: 87808 tok + 21952 aux + 2058 coords.
// I/O f32; intermediates bf16 in ws (256 MiB exactly). Stats live in d_out
// (overwritten by k_final at the end).

typedef __hip_bfloat16 bf16;
__device__ __forceinline__ float b2f(bf16 v){ return __bfloat162float(v); }
__device__ __forceinline__ bf16 f2b(float v){ return __float2bfloat16(v); }

#define SP12 2097152   // 128^3
#define SP3  262144    // 64^3
#define M_TOT 686
#define TOK_OFF 0
#define AUX_OFF 87808
#define CRD_OFF 109760

// ---------------- conv1: (2,1,128^3) -> (2,16,128^3) raw, pad=1 -------------
__global__ __launch_bounds__(256) void k_conv1(const float* __restrict__ x,
                                               const float* __restrict__ w,
                                               bf16* __restrict__ y1){
  __shared__ float wl[432];           // [oc16][27]
  for(int i=threadIdx.x;i<432;i+=256) wl[i]=w[i];
  __syncthreads();
  int t = blockIdx.x*256 + threadIdx.x;
  int xx = t & 127; int yy = (t>>7)&127; int zz = (t>>14)&127; int b = t>>21;
  float acc[16];
#pragma unroll
  for(int o=0;o<16;o++) acc[o]=0.f;
  const float* xb = x + (size_t)b*SP12;
#pragma unroll
  for(int dz=0;dz<3;dz++){
    int iz = zz-1+dz; if((unsigned)iz >= 128u) continue;
#pragma unroll
    for(int dy=0;dy<3;dy++){
      int iy = yy-1+dy; if((unsigned)iy >= 128u) continue;
      const float* row = xb + iz*16384 + iy*128;
#pragma unroll
      for(int dx=0;dx<3;dx++){
        int ix = xx-1+dx; bool ok = (unsigned)ix < 128u;
        float v = row[ok?ix:0]; v = ok? v : 0.f;
        int wi = (dz*3+dy)*3+dx;
#pragma unroll
        for(int o=0;o<16;o++) acc[o] += v*wl[o*27+wi];
      }
    }
  }
  int sp = zz*16384 + yy*128 + xx;
#pragma unroll
  for(int o=0;o<16;o++) y1[(size_t)(b*16+o)*SP12 + sp] = f2b(acc[o]);
}

// ---------------- per-channel sum/sumsq over [b=2][C][SP], 8 bf16/load ------
__device__ __forceinline__ void acc2(unsigned u, float& s, float& q){
  float a = __uint_as_float(u<<16);
  float b = __uint_as_float(u & 0xffff0000u);
  s += a+b; q += a*a+b*b;
}
__global__ __launch_bounds__(256) void k_stats(const bf16* __restrict__ buf,
                                               float* __restrict__ sums,
                                               int C, int SP, int nslab, int chunkV){
  int c = blockIdx.x / nslab; int slab = blockIdx.x % nslab;
  int V = SP >> 3;
  int i0 = slab*chunkV; int i1 = i0+chunkV; if(i1 > V) i1 = V;
  const uint4* p0 = (const uint4*)(buf + (size_t)c*SP);
  const uint4* p1 = (const uint4*)(buf + (size_t)(C+c)*SP);
  float s=0.f, q=0.f;
  for(int i=i0+threadIdx.x; i<i1; i+=256){
    uint4 u = p0[i];
    acc2(u.x,s,q); acc2(u.y,s,q); acc2(u.z,s,q); acc2(u.w,s,q);
    uint4 v = p1[i];
    acc2(v.x,s,q); acc2(v.y,s,q); acc2(v.z,s,q); acc2(v.w,s,q);
  }
  __shared__ float rs[4], rq[4];
#pragma unroll
  for(int off=32;off>0;off>>=1){ s += __shfl_down(s,off); q += __shfl_down(q,off); }
  int lane = threadIdx.x & 63; int wv = threadIdx.x >> 6;
  if(lane==0){ rs[wv]=s; rq[wv]=q; }
  __syncthreads();
  if(threadIdx.x==0){
    atomicAdd(&sums[c],   rs[0]+rs[1]+rs[2]+rs[3]);
    atomicAdd(&sums[C+c], rq[0]+rq[1]+rq[2]+rq[3]);
  }
}

// ------------- scale/shift: scale=g*rsqrt(var+eps), shift=b-mean*scale ------
__global__ void k_finalize(const float* __restrict__ sums, const float* __restrict__ g,
                           const float* __restrict__ bb, float* __restrict__ scsh,
                           int C, float invN){
  int i = threadIdx.x;
  if(i<C){
    float mean = sums[i]*invN;
    float var  = sums[C+i]*invN - mean*mean;
    float sc = g[i]*rsqrtf(var+1e-5f);
    scsh[i]   = sc;
    scsh[C+i] = bb[i] - mean*sc;
  }
}

// ---------------- conv2: bn1+relu on read, pad=1, (2,16,128^3)->(2,16,128^3)
// thread = 4 consecutive x outputs x 16 oc. 128 = 32*4.
__global__ __launch_bounds__(256) void k_conv2(const bf16* __restrict__ y1,
                                               const float* __restrict__ w,
                                               const float* __restrict__ scsh,
                                               bf16* __restrict__ y2){
  __shared__ float wl[6912];          // [ic16][27][oc16]
  for(int i=threadIdx.x;i<6912;i+=256){
    int oc = i & 15; int k = (i>>4) % 27; int ic = i/432;
    wl[i] = w[(oc*16+ic)*27 + k];
  }
  __syncthreads();
  int t = blockIdx.x*256+threadIdx.x;
  int xq = t & 31; int yy = (t>>5)&127; int zz = (t>>12)&127; int b = t>>19;
  int x0 = xq*4;
  float acc[16][4];
#pragma unroll
  for(int o=0;o<16;o++)
#pragma unroll
    for(int j=0;j<4;j++) acc[o][j]=0.f;
  for(int ic=0;ic<16;ic++){
    float sc = scsh[ic], sh = scsh[16+ic];
    const bf16* base = y1 + (size_t)(b*16+ic)*SP12;
#pragma unroll
    for(int dz=0;dz<3;dz++){
      int iz = zz-1+dz; if((unsigned)iz>=128u) continue;
#pragma unroll
      for(int dy=0;dy<3;dy++){
        int iy = yy-1+dy; if((unsigned)iy>=128u) continue;
        const bf16* row = base + iz*16384 + iy*128;
        float in[6];
#pragma unroll
        for(int j=0;j<6;j++){
          int ix = x0-1+j; bool ok = (unsigned)ix < 128u;
          float raw = b2f(row[ok?ix:0]);
          in[j] = ok ? fmaxf(raw*sc+sh, 0.f) : 0.f;
        }
        const float* wp = &wl[(ic*27 + (dz*3+dy)*3)*16];
#pragma unroll
        for(int dx=0;dx<3;dx++){
          const float4* w4 = (const float4*)(wp + dx*16);
#pragma unroll
          for(int oq=0;oq<4;oq++){
            float4 wv = w4[oq];
#pragma unroll
            for(int xi=0;xi<4;xi++){
              float v = in[dx+xi];
              acc[oq*4+0][xi] += v*wv.x;
              acc[oq*4+1][xi] += v*wv.y;
              acc[oq*4+2][xi] += v*wv.z;
              acc[oq*4+3][xi] += v*wv.w;
            }
          }
        }
      }
    }
  }
  int spb = zz*16384 + yy*128 + x0;
#pragma unroll
  for(int o=0;o<16;o++){
    bf16* qp = y2 + (size_t)(b*16+o)*SP12 + spb;
#pragma unroll
    for(int j=0;j<4;j++) qp[j] = f2b(acc[o][j]);
  }
}

// ---------------- conv3 stride2 pad1: bn2+relu on read, ->(2,32,64^3) raw ---
__global__ __launch_bounds__(256) void k_conv3(const bf16* __restrict__ y2,
                                               const float* __restrict__ w,
                                               const float* __restrict__ scsh,
                                               bf16* __restrict__ f0){
  __shared__ float wl[13824];         // [ic16][27][oc32]
  for(int i=threadIdx.x;i<13824;i+=256){
    int oc = i & 31; int k = (i>>5) % 27; int ic = i/864;
    wl[i] = w[(oc*16+ic)*27+k];
  }
  __syncthreads();
  int t = blockIdx.x*256+threadIdx.x;
  int xx = t & 63; int yy = (t>>6)&63; int zz = (t>>12)&63; int b = t>>18;
  float acc[32];
#pragma unroll
  for(int o=0;o<32;o++) acc[o]=0.f;
  for(int ic=0;ic<16;ic++){
    float sc=scsh[ic], sh=scsh[16+ic];
    const bf16* base = y2 + (size_t)(b*16+ic)*SP12;
#pragma unroll
    for(int dz=0;dz<3;dz++){
      int iz = 2*zz-1+dz; if(iz < 0) continue;     // max 127, only low guard
#pragma unroll
      for(int dy=0;dy<3;dy++){
        int iy = 2*yy-1+dy; if(iy < 0) continue;
        const bf16* row = base + iz*16384 + iy*128;
        const float* wp = &wl[(ic*27 + (dz*3+dy)*3)*32];
#pragma unroll
        for(int dx=0;dx<3;dx++){
          int ix = 2*xx-1+dx; bool ok = ix >= 0;
          float raw = b2f(row[ok?ix:0]);
          float v = ok ? fmaxf(raw*sc+sh,0.f) : 0.f;
          const float4* w4 = (const float4*)(wp + dx*32);
#pragma unroll
          for(int oq=0;oq<8;oq++){
            float4 wv = w4[oq];
            acc[oq*4+0] += v*wv.x; acc[oq*4+1] += v*wv.y;
            acc[oq*4+2] += v*wv.z; acc[oq*4+3] += v*wv.w;
          }
        }
      }
    }
  }
  int sp = zz*4096 + yy*64 + xx;
#pragma unroll
  for(int o=0;o<32;o++) f0[(size_t)(b*32+o)*SP3 + sp] = f2b(acc[o]);
}

// ---------------- projection GEMM: M=686, N=160, K=131072 -------------------
// bn3+relu applied on the patch gather. grid = Ksplit(64) x Mtiles(15).
__global__ __launch_bounds__(256) void k_gemm(const bf16* __restrict__ f0,
                                              const float* __restrict__ tokw,
                                              const float* __restrict__ auxw,
                                              const float* __restrict__ scsh3,
                                              float* __restrict__ out_acc){
  __shared__ float Wl[160*66];
  __shared__ float Al[48*66];
  int mt = blockIdx.x % 15; int ks = blockIdx.x / 15;
  int m0 = mt*48; int kb = ks*2048;
  int tn = threadIdx.x & 31; int tm = threadIdx.x >> 5;   // 32 x 8
  float2 acc[5][6];
#pragma unroll
  for(int i=0;i<5;i++)
#pragma unroll
    for(int j=0;j<6;j++){ acc[i][j].x=0.f; acc[i][j].y=0.f; }
  for(int sub=0; sub<32; sub++){
    int k0 = kb + sub*64;
    __syncthreads();
    // stage W[160][64]
#pragma unroll
    for(int tp=0;tp<40;tp++){
      int idx = threadIdx.x + tp*256;
      int n = idx >> 6; int kk = idx & 63;
      float v = (n<128) ? tokw[(size_t)n*131072 + k0+kk]
                        : auxw[(size_t)(n-128)*131072 + k0+kk];
      Wl[n*66+kk] = v;
    }
    // stage A[48][64]: gather from f0 with bn3+relu
    int c = k0 >> 12;                       // constant over the 64-wide k block
    float sc = scsh3[c], sh = scsh3[32+c];
#pragma unroll
    for(int tp=0;tp<12;tp++){
      int idx = threadIdx.x + tp*256;
      int m = idx >> 6; int kk = idx & 63;
      int mg = m0+m; if(mg > 685) mg = 685;
      int b = mg/343; int r = mg%343;
      int nz = r/49; int rem = r%49; int ny = rem/7; int nx = rem - ny*7;
      int kg = k0+kk;
      int kz = (kg>>8)&15; int ky=(kg>>4)&15; int kx = kg&15;
      float raw = b2f(f0[(size_t)(b*32+c)*SP3 + (nz*8+kz)*4096 + (ny*8+ky)*64 + (nx*8+kx)]);
      Al[m*66+kk] = fmaxf(raw*sc+sh, 0.f);
    }
    __syncthreads();
#pragma unroll 8
    for(int kk=0;kk<64;kk+=2){
      float2 av[6], wv[5];
#pragma unroll
      for(int j=0;j<6;j++) av[j] = *(const float2*)&Al[(tm+j*8)*66+kk];
#pragma unroll
      for(int i=0;i<5;i++) wv[i] = *(const float2*)&Wl[(tn+i*32)*66+kk];
#pragma unroll
      for(int i=0;i<5;i++)
#pragma unroll
        for(int j=0;j<6;j++){
          acc[i][j].x += av[j].x*wv[i].x;
          acc[i][j].y += av[j].y*wv[i].y;
        }
    }
  }
#pragma unroll
  for(int i=0;i<5;i++)
#pragma unroll
    for(int j=0;j<6;j++){
      int m = m0 + tm + j*8; int n = tn + i*32;
      if(m < M_TOT)
        out_acc[(size_t)(ks*M_TOT+m)*160 + n] = acc[i][j].x + acc[i][j].y;
    }
}

// ------------- reduce split-K, +bias, LN(tokens), coords, write out ---------
__global__ __launch_bounds__(256) void k_final(const float* __restrict__ out_acc,
                                               const float* __restrict__ tok_b,
                                               const float* __restrict__ aux_b,
                                               const float* __restrict__ ln_g,
                                               const float* __restrict__ ln_b,
                                               float* __restrict__ out){
  int m = blockIdx.x;            // 0..685
  int n = threadIdx.x;
  __shared__ float sA[128], sB[128];
  float sum = 0.f;
  if(n < 160){
    for(int ks=0;ks<64;ks++) sum += out_acc[(size_t)(ks*M_TOT+m)*160 + n];
  }
  float tval = 0.f;
  if(n < 128){
    tval = sum + tok_b[n];
    sA[n] = tval; sB[n] = tval*tval;
  }
  __syncthreads();
  for(int s=64;s>0;s>>=1){
    if(n < s){ sA[n] += sA[n+s]; sB[n] += sB[n+s]; }
    __syncthreads();
  }
  float mean = sA[0]*(1.f/128.f);
  float var  = sB[0]*(1.f/128.f) - mean*mean;
  float rstd = rsqrtf(var + 1e-5f);
  if(n<128){
    out[TOK_OFF + (size_t)m*128 + n] = (tval-mean)*rstd*ln_g[n] + ln_b[n];
  } else if(n<160){
    out[AUX_OFF + (size_t)m*32 + (n-128)] = sum + aux_b[n-128];
  } else if(n<163){
    int j = n-160;
    int pn = m % 343;
    int nz = pn/49, ny=(pn/7)%7, nx=pn%7;
    int g = (j==0)? nz : (j==1)? ny : nx;
    out[CRD_OFF + (size_t)m*3 + j] = (g*8 + 7.5f)*(1.f/63.f);
  }
}

extern "C" void kernel_launch(void* const* d_in, const int* in_sizes, int n_in,
                              void* d_out, int out_size, void* d_ws, size_t ws_size,
                              hipStream_t stream){
  const float* x    = (const float*)d_in[0];
  const float* w1   = (const float*)d_in[1];
  const float* g1   = (const float*)d_in[2];
  const float* b1   = (const float*)d_in[3];
  const float* w2   = (const float*)d_in[4];
  const float* g2   = (const float*)d_in[5];
  const float* b2   = (const float*)d_in[6];
  const float* w3   = (const float*)d_in[7];
  const float* g3   = (const float*)d_in[8];
  const float* b3   = (const float*)d_in[9];
  const float* tokw = (const float*)d_in[10];
  const float* tokb = (const float*)d_in[11];
  const float* auxw = (const float*)d_in[12];
  const float* auxb = (const float*)d_in[13];
  const float* lng  = (const float*)d_in[14];
  const float* lnb  = (const float*)d_in[15];
  float* out = (float*)d_out;

  // ws layout (256 MiB): y1 [0,128Mi), y2 [128Mi,256Mi).
  // After conv2, y1 region reused: f0 [0,32Mi), out_acc [32Mi, +28.1MB).
  // Stats (256 f32) live in d_out[0..255] — dead before k_final overwrites.
  char* ws = (char*)d_ws;
  bf16*  y1      = (bf16*)ws;
  bf16*  y2      = (bf16*)(ws + 134217728);
  bf16*  f0      = (bf16*)ws;
  float* out_acc = (float*)(ws + 33554432);
  float* stats   = (float*)d_out;
  float* sums1 = stats;        float* sums2 = stats+32;  float* sums3 = stats+64;
  float* scsh1 = stats+128;    float* scsh2 = stats+160; float* scsh3 = stats+192;

  hipMemsetAsync(stats, 0, 512, stream);

  k_conv1<<<16384, 256, 0, stream>>>(x, w1, y1);
  k_stats<<<16*64, 256, 0, stream>>>(y1, sums1, 16, SP12, 64, 4096);
  k_finalize<<<1, 64, 0, stream>>>(sums1, g1, b1, scsh1, 16, 1.f/4194304.f);
  k_conv2<<<4096, 256, 0, stream>>>(y1, w2, scsh1, y2);
  k_stats<<<16*64, 256, 0, stream>>>(y2, sums2, 16, SP12, 64, 4096);
  k_finalize<<<1, 64, 0, stream>>>(sums2, g2, b2, scsh2, 16, 1.f/4194304.f);
  k_conv3<<<2048, 256, 0, stream>>>(y2, w3, scsh2, f0);
  k_stats<<<32*32, 256, 0, stream>>>(f0, sums3, 32, SP3, 32, 1024);
  k_finalize<<<1, 64, 0, stream>>>(sums3, g3, b3, scsh3, 32, 1.f/524288.f);
  k_gemm<<<960, 256, 0, stream>>>(f0, tokw, auxw, scsh3, out_acc);
  k_final<<<686, 256, 0, stream>>>(out_acc, tokb, auxb, lng, lnb, out);
}

// Round 4
// 1427.930 us; speedup vs baseline: 2.8016x; 2.8016x over previous
//
#include <hip/hip_runtime.h>
#include <hip/hip_bf16.h>

// Geometry (pad=1 convs): conv1/conv2 -> (2,16,128^3), conv3 s2 -> (2,32,64^3)
// patches: 7^3 per batch, M=686, pdim=131072. I/O f32; intermediates bf16.
// Round 3: MFMA bf16 projection GEMM (was 2590us fp32-latency-bound).

typedef __hip_bfloat16 bf16;
typedef __attribute__((ext_vector_type(8))) short short8;   // 8 bf16 = 4 VGPR
typedef __attribute__((ext_vector_type(4))) float f32x4;
__device__ __forceinline__ float b2f(bf16 v){ return __bfloat162float(v); }
__device__ __forceinline__ bf16 f2b(float v){ return __float2bfloat16(v); }
__device__ __forceinline__ unsigned short f2bu(float f){   // RNE, no aliasing
  unsigned u = __float_as_uint(f);
  return (unsigned short)((u + 0x7fff + ((u>>16)&1)) >> 16);
}

#define SP12 2097152   // 128^3
#define SP3  262144    // 64^3
#define M_TOT 686
#define TOK_OFF 0
#define AUX_OFF 87808
#define CRD_OFF 109760
#define KSPLIT 32

// ---------------- conv1: (2,1,128^3) -> (2,16,128^3) raw, pad=1 -------------
__global__ __launch_bounds__(256) void k_conv1(const float* __restrict__ x,
                                               const float* __restrict__ w,
                                               bf16* __restrict__ y1){
  __shared__ float wl[432];           // [oc16][27]
  for(int i=threadIdx.x;i<432;i+=256) wl[i]=w[i];
  __syncthreads();
  int t = blockIdx.x*256 + threadIdx.x;
  int xx = t & 127; int yy = (t>>7)&127; int zz = (t>>14)&127; int b = t>>21;
  float acc[16];
#pragma unroll
  for(int o=0;o<16;o++) acc[o]=0.f;
  const float* xb = x + (size_t)b*SP12;
#pragma unroll
  for(int dz=0;dz<3;dz++){
    int iz = zz-1+dz; if((unsigned)iz >= 128u) continue;
#pragma unroll
    for(int dy=0;dy<3;dy++){
      int iy = yy-1+dy; if((unsigned)iy >= 128u) continue;
      const float* row = xb + iz*16384 + iy*128;
#pragma unroll
      for(int dx=0;dx<3;dx++){
        int ix = xx-1+dx; bool ok = (unsigned)ix < 128u;
        float v = row[ok?ix:0]; v = ok? v : 0.f;
        int wi = (dz*3+dy)*3+dx;
#pragma unroll
        for(int o=0;o<16;o++) acc[o] += v*wl[o*27+wi];
      }
    }
  }
  int sp = zz*16384 + yy*128 + xx;
#pragma unroll
  for(int o=0;o<16;o++) y1[(size_t)(b*16+o)*SP12 + sp] = f2b(acc[o]);
}

// ---------------- per-channel sum/sumsq over [b=2][C][SP], 8 bf16/load ------
__device__ __forceinline__ void acc2(unsigned u, float& s, float& q){
  float a = __uint_as_float(u<<16);
  float b = __uint_as_float(u & 0xffff0000u);
  s += a+b; q += a*a+b*b;
}
__global__ __launch_bounds__(256) void k_stats(const bf16* __restrict__ buf,
                                               float* __restrict__ sums,
                                               int C, int SP, int nslab, int chunkV){
  int c = blockIdx.x / nslab; int slab = blockIdx.x % nslab;
  int V = SP >> 3;
  int i0 = slab*chunkV; int i1 = i0+chunkV; if(i1 > V) i1 = V;
  const uint4* p0 = (const uint4*)(buf + (size_t)c*SP);
  const uint4* p1 = (const uint4*)(buf + (size_t)(C+c)*SP);
  float s=0.f, q=0.f;
  for(int i=i0+threadIdx.x; i<i1; i+=256){
    uint4 u = p0[i];
    acc2(u.x,s,q); acc2(u.y,s,q); acc2(u.z,s,q); acc2(u.w,s,q);
    uint4 v = p1[i];
    acc2(v.x,s,q); acc2(v.y,s,q); acc2(v.z,s,q); acc2(v.w,s,q);
  }
  __shared__ float rs[4], rq[4];
#pragma unroll
  for(int off=32;off>0;off>>=1){ s += __shfl_down(s,off); q += __shfl_down(q,off); }
  int lane = threadIdx.x & 63; int wv = threadIdx.x >> 6;
  if(lane==0){ rs[wv]=s; rq[wv]=q; }
  __syncthreads();
  if(threadIdx.x==0){
    atomicAdd(&sums[c],   rs[0]+rs[1]+rs[2]+rs[3]);
    atomicAdd(&sums[C+c], rq[0]+rq[1]+rq[2]+rq[3]);
  }
}

// ------------- scale/shift: scale=g*rsqrt(var+eps), shift=b-mean*scale ------
__global__ void k_finalize(const float* __restrict__ sums, const float* __restrict__ g,
                           const float* __restrict__ bb, float* __restrict__ scsh,
                           int C, float invN){
  int i = threadIdx.x;
  if(i<C){
    float mean = sums[i]*invN;
    float var  = sums[C+i]*invN - mean*mean;
    float sc = g[i]*rsqrtf(var+1e-5f);
    scsh[i]   = sc;
    scsh[C+i] = bb[i] - mean*sc;
  }
}

// ---------------- conv2: bn1+relu on read, pad=1, (2,16,128^3)->(2,16,128^3)
__global__ __launch_bounds__(256) void k_conv2(const bf16* __restrict__ y1,
                                               const float* __restrict__ w,
                                               const float* __restrict__ scsh,
                                               bf16* __restrict__ y2){
  __shared__ float wl[6912];          // [ic16][27][oc16]
  for(int i=threadIdx.x;i<6912;i+=256){
    int oc = i & 15; int k = (i>>4) % 27; int ic = i/432;
    wl[i] = w[(oc*16+ic)*27 + k];
  }
  __syncthreads();
  int t = blockIdx.x*256+threadIdx.x;
  int xq = t & 31; int yy = (t>>5)&127; int zz = (t>>12)&127; int b = t>>19;
  int x0 = xq*4;
  float acc[16][4];
#pragma unroll
  for(int o=0;o<16;o++)
#pragma unroll
    for(int j=0;j<4;j++) acc[o][j]=0.f;
  for(int ic=0;ic<16;ic++){
    float sc = scsh[ic], sh = scsh[16+ic];
    const bf16* base = y1 + (size_t)(b*16+ic)*SP12;
#pragma unroll
    for(int dz=0;dz<3;dz++){
      int iz = zz-1+dz; if((unsigned)iz>=128u) continue;
#pragma unroll
      for(int dy=0;dy<3;dy++){
        int iy = yy-1+dy; if((unsigned)iy>=128u) continue;
        const bf16* row = base + iz*16384 + iy*128;
        float in[6];
#pragma unroll
        for(int j=0;j<6;j++){
          int ix = x0-1+j; bool ok = (unsigned)ix < 128u;
          float raw = b2f(row[ok?ix:0]);
          in[j] = ok ? fmaxf(raw*sc+sh, 0.f) : 0.f;
        }
        const float* wp = &wl[(ic*27 + (dz*3+dy)*3)*16];
#pragma unroll
        for(int dx=0;dx<3;dx++){
          const float4* w4 = (const float4*)(wp + dx*16);
#pragma unroll
          for(int oq=0;oq<4;oq++){
            float4 wv = w4[oq];
#pragma unroll
            for(int xi=0;xi<4;xi++){
              float v = in[dx+xi];
              acc[oq*4+0][xi] += v*wv.x;
              acc[oq*4+1][xi] += v*wv.y;
              acc[oq*4+2][xi] += v*wv.z;
              acc[oq*4+3][xi] += v*wv.w;
            }
          }
        }
      }
    }
  }
  int spb = zz*16384 + yy*128 + x0;
#pragma unroll
  for(int o=0;o<16;o++){
    bf16* qp = y2 + (size_t)(b*16+o)*SP12 + spb;
#pragma unroll
    for(int j=0;j<4;j++) qp[j] = f2b(acc[o][j]);
  }
}

// ---------------- conv3 stride2 pad1: bn2+relu on read, ->(2,32,64^3) raw ---
__global__ __launch_bounds__(256) void k_conv3(const bf16* __restrict__ y2,
                                               const float* __restrict__ w,
                                               const float* __restrict__ scsh,
                                               bf16* __restrict__ f0){
  __shared__ float wl[13824];         // [ic16][27][oc32]
  for(int i=threadIdx.x;i<13824;i+=256){
    int oc = i & 31; int k = (i>>5) % 27; int ic = i/864;
    wl[i] = w[(oc*16+ic)*27+k];
  }
  __syncthreads();
  int t = blockIdx.x*256+threadIdx.x;
  int xx = t & 63; int yy = (t>>6)&63; int zz = (t>>12)&63; int b = t>>18;
  float acc[32];
#pragma unroll
  for(int o=0;o<32;o++) acc[o]=0.f;
  for(int ic=0;ic<16;ic++){
    float sc=scsh[ic], sh=scsh[16+ic];
    const bf16* base = y2 + (size_t)(b*16+ic)*SP12;
#pragma unroll
    for(int dz=0;dz<3;dz++){
      int iz = 2*zz-1+dz; if(iz < 0) continue;
#pragma unroll
      for(int dy=0;dy<3;dy++){
        int iy = 2*yy-1+dy; if(iy < 0) continue;
        const bf16* row = base + iz*16384 + iy*128;
        const float* wp = &wl[(ic*27 + (dz*3+dy)*3)*32];
#pragma unroll
        for(int dx=0;dx<3;dx++){
          int ix = 2*xx-1+dx; bool ok = ix >= 0;
          float raw = b2f(row[ok?ix:0]);
          float v = ok ? fmaxf(raw*sc+sh,0.f) : 0.f;
          const float4* w4 = (const float4*)(wp + dx*32);
#pragma unroll
          for(int oq=0;oq<8;oq++){
            float4 wv = w4[oq];
            acc[oq*4+0] += v*wv.x; acc[oq*4+1] += v*wv.y;
            acc[oq*4+2] += v*wv.z; acc[oq*4+3] += v*wv.w;
          }
        }
      }
    }
  }
  int sp = zz*4096 + yy*64 + xx;
#pragma unroll
  for(int o=0;o<32;o++) f0[(size_t)(b*32+o)*SP3 + sp] = f2b(acc[o]);
}

// ---------------- W f32 -> bf16 pre-convert: wb[160][131072] ----------------
__global__ __launch_bounds__(256) void k_cvtw(const float* __restrict__ tokw,
                                              const float* __restrict__ auxw,
                                              unsigned short* __restrict__ wb){
  int i = blockIdx.x*256 + threadIdx.x;        // float4 group id, 5,242,880 total
  int n = i >> 15;                              // 32768 groups per row
  int g = i & 32767;
  const float* src = (n<128)? tokw + (size_t)n*131072 : auxw + (size_t)(n-128)*131072;
  float4 v = *(const float4*)(src + g*4);
  ushort4 o; o.x=f2bu(v.x); o.y=f2bu(v.y); o.z=f2bu(v.z); o.w=f2bu(v.w);
  *(ushort4*)(wb + (size_t)n*131072 + g*4) = o;
}

// ---------------- MFMA projection GEMM: M=686, N=160, K=131072 --------------
// grid = 11 mblk x 32 ksplit. Each block: K-range 4096 = exactly channel c=ks.
// BK=64. LDS A[64][72] bf16, W[160][72] bf16 (pad 8 -> 2-way bank = free).
// 4 waves in 2x2: wave m-off {0,32}, n-off {0,80}; per wave 2x5 16x16 tiles.
__global__ __launch_bounds__(256) void k_gemm(const bf16* __restrict__ f0,
                                              const unsigned short* __restrict__ wb,
                                              const float* __restrict__ scsh3,
                                              float* __restrict__ out_acc){
  __shared__ unsigned short Al[64*72];
  __shared__ unsigned short Wl[160*72];
  int mblk = blockIdx.x % 11; int ks = blockIdx.x / 11;
  int M0 = mblk*64;
  int c  = ks;                                  // 4096 K per channel
  float sc = scsh3[c], sh = scsh3[32+c];
  int t = threadIdx.x;
  int lane = t & 63; int wid = t >> 6;
  int wm = (wid & 1)*32; int wn = (wid >> 1)*80;
  f32x4 acc[2][5];
#pragma unroll
  for(int i=0;i<2;i++)
#pragma unroll
    for(int j=0;j<5;j++) acc[i][j] = (f32x4){0.f,0.f,0.f,0.f};

  // A-gather per-thread constants: 2 chunks j = t, t+256; j: m=j>>3, ch=j&7
  int ky_off0 = (t&7)>>1, half0 = t&1;          // chunk for j=t
  // j2 = t+256 -> m2 = m+32, same chunk bits
  int m_a = t>>3;
  int mg1 = M0 + m_a;       if(mg1>685) mg1=685;
  int mg2 = M0 + m_a + 32;  if(mg2>685) mg2=685;
  int b1 = mg1/343, r1 = mg1%343;
  int b2 = mg2/343, r2 = mg2%343;
  int sp1 = ((r1/49)*8)*4096 + (((r1/7)%7)*8)*64 + (r1%7)*8;
  int sp2 = ((r2/49)*8)*4096 + (((r2/7)%7)*8)*64 + (r2%7)*8;
  const bf16* f0c1 = f0 + (size_t)(b1*32+c)*SP3;
  const bf16* f0c2 = f0 + (size_t)(b2*32+c)*SP3;

  for(int bk=0; bk<64; bk++){
    int kz = bk>>2; int kyb = (bk&3)*4;
    __syncthreads();
    // stage W[160][64]: 5 passes, dwordx4 (8 bf16) each
#pragma unroll
    for(int p=0;p<5;p++){
      int n = p*32 + (t>>3);
      int koff = (t&7)*8;
      uint4 v = *(const uint4*)(wb + (size_t)n*131072 + ks*4096 + bk*64 + koff);
      *(uint4*)&Wl[n*72 + koff] = v;
    }
    // stage A[64][64]: 2 chunks with fused bn3+relu
    {
      int ky = kyb + ky_off0; int xo = half0*8;
      int ldso = ky_off0*16 + half0*8;
      uint4 u1 = *(const uint4*)(f0c1 + sp1 + (kz)*4096 + ky*64 + xo);
      uint4 u2 = *(const uint4*)(f0c2 + sp2 + (kz)*4096 + ky*64 + xo);
      unsigned uu[8]; uu[0]=u1.x; uu[1]=u1.y; uu[2]=u1.z; uu[3]=u1.w;
      uu[4]=u2.x; uu[5]=u2.y; uu[6]=u2.z; uu[7]=u2.w;
      unsigned outw[8];
#pragma unroll
      for(int q=0;q<8;q++){
        float lo = fmaxf(__uint_as_float(uu[q]<<16)*sc + sh, 0.f);
        float hi = fmaxf(__uint_as_float(uu[q]&0xffff0000u)*sc + sh, 0.f);
        outw[q] = (unsigned)f2bu(lo) | ((unsigned)f2bu(hi)<<16);
      }
      uint4 w1; w1.x=outw[0]; w1.y=outw[1]; w1.z=outw[2]; w1.w=outw[3];
      uint4 w2; w2.x=outw[4]; w2.y=outw[5]; w2.z=outw[6]; w2.w=outw[7];
      *(uint4*)&Al[m_a*72 + ldso] = w1;
      *(uint4*)&Al[(m_a+32)*72 + ldso] = w2;
    }
    __syncthreads();
    // compute: 2 k-steps of 32
#pragma unroll
    for(int kstep=0;kstep<2;kstep++){
      int ko = kstep*32 + (lane>>4)*8;
      short8 af[2], bfr[5];
#pragma unroll
      for(int mt=0;mt<2;mt++)
        af[mt] = *(const short8*)&Al[(wm + mt*16 + (lane&15))*72 + ko];
#pragma unroll
      for(int nt=0;nt<5;nt++)
        bfr[nt] = *(const short8*)&Wl[(wn + nt*16 + (lane&15))*72 + ko];
#pragma unroll
      for(int mt=0;mt<2;mt++)
#pragma unroll
        for(int nt=0;nt<5;nt++)
          acc[mt][nt] = __builtin_amdgcn_mfma_f32_16x16x32_bf16(af[mt], bfr[nt], acc[mt][nt], 0,0,0);
    }
  }
  // epilogue: m = (lane>>4)*4 + reg, n = lane&15 (m89-verified C/D layout)
#pragma unroll
  for(int mt=0;mt<2;mt++){
    int mb = M0 + wm + mt*16 + (lane>>4)*4;
#pragma unroll
    for(int nt=0;nt<5;nt++){
      int n = wn + nt*16 + (lane&15);
#pragma unroll
      for(int reg=0;reg<4;reg++){
        int m = mb + reg;
        if(m < M_TOT)
          out_acc[((size_t)ks*M_TOT + m)*160 + n] = acc[mt][nt][reg];
      }
    }
  }
}

// ------------- reduce split-K, +bias, LN(tokens), coords, write out ---------
__global__ __launch_bounds__(256) void k_final(const float* __restrict__ out_acc,
                                               const float* __restrict__ tok_b,
                                               const float* __restrict__ aux_b,
                                               const float* __restrict__ ln_g,
                                               const float* __restrict__ ln_b,
                                               float* __restrict__ out){
  int m = blockIdx.x;            // 0..685
  int n = threadIdx.x;
  __shared__ float sA[128], sB[128];
  float sum = 0.f;
  if(n < 160){
    for(int ks=0;ks<KSPLIT;ks++) sum += out_acc[((size_t)ks*M_TOT+m)*160 + n];
  }
  float tval = 0.f;
  if(n < 128){
    tval = sum + tok_b[n];
    sA[n] = tval; sB[n] = tval*tval;
  }
  __syncthreads();
  for(int s=64;s>0;s>>=1){
    if(n < s){ sA[n] += sA[n+s]; sB[n] += sB[n+s]; }
    __syncthreads();
  }
  float mean = sA[0]*(1.f/128.f);
  float var  = sB[0]*(1.f/128.f) - mean*mean;
  float rstd = rsqrtf(var + 1e-5f);
  if(n<128){
    out[TOK_OFF + (size_t)m*128 + n] = (tval-mean)*rstd*ln_g[n] + ln_b[n];
  } else if(n<160){
    out[AUX_OFF + (size_t)m*32 + (n-128)] = sum + aux_b[n-128];
  } else if(n<163){
    int j = n-160;
    int pn = m % 343;
    int nz = pn/49, ny=(pn/7)%7, nx=pn%7;
    int g = (j==0)? nz : (j==1)? ny : nx;
    out[CRD_OFF + (size_t)m*3 + j] = (g*8 + 7.5f)*(1.f/63.f);
  }
}

extern "C" void kernel_launch(void* const* d_in, const int* in_sizes, int n_in,
                              void* d_out, int out_size, void* d_ws, size_t ws_size,
                              hipStream_t stream){
  const float* x    = (const float*)d_in[0];
  const float* w1   = (const float*)d_in[1];
  const float* g1   = (const float*)d_in[2];
  const float* b1   = (const float*)d_in[3];
  const float* w2   = (const float*)d_in[4];
  const float* g2   = (const float*)d_in[5];
  const float* b2   = (const float*)d_in[6];
  const float* w3   = (const float*)d_in[7];
  const float* g3   = (const float*)d_in[8];
  const float* b3   = (const float*)d_in[9];
  const float* tokw = (const float*)d_in[10];
  const float* tokb = (const float*)d_in[11];
  const float* auxw = (const float*)d_in[12];
  const float* auxb = (const float*)d_in[13];
  const float* lng  = (const float*)d_in[14];
  const float* lnb  = (const float*)d_in[15];
  float* out = (float*)d_out;

  // ws layout (256 MiB): y1 [0,128Mi), y2 [128Mi,256Mi).
  // After conv2, region0 reused: f0 [0,32Mi), out_acc [32Mi,+14.05MB),
  // Wbf16 [64Mi, 64Mi+41.9MB). Stats (256 f32) in d_out[0..255] (dead before
  // k_final overwrites).
  char* ws = (char*)d_ws;
  bf16*  y1      = (bf16*)ws;
  bf16*  y2      = (bf16*)(ws + 134217728);
  bf16*  f0      = (bf16*)ws;
  float* out_acc = (float*)(ws + 33554432);
  unsigned short* wbf = (unsigned short*)(ws + 67108864);
  float* stats   = (float*)d_out;
  float* sums1 = stats;        float* sums2 = stats+32;  float* sums3 = stats+64;
  float* scsh1 = stats+128;    float* scsh2 = stats+160; float* scsh3 = stats+192;

  hipMemsetAsync(stats, 0, 512, stream);

  k_conv1<<<16384, 256, 0, stream>>>(x, w1, y1);
  k_stats<<<16*64, 256, 0, stream>>>(y1, sums1, 16, SP12, 64, 4096);
  k_finalize<<<1, 64, 0, stream>>>(sums1, g1, b1, scsh1, 16, 1.f/4194304.f);
  k_conv2<<<4096, 256, 0, stream>>>(y1, w2, scsh1, y2);
  k_stats<<<16*64, 256, 0, stream>>>(y2, sums2, 16, SP12, 64, 4096);
  k_finalize<<<1, 64, 0, stream>>>(sums2, g2, b2, scsh2, 16, 1.f/4194304.f);
  k_conv3<<<2048, 256, 0, stream>>>(y2, w3, scsh2, f0);
  k_cvtw<<<20480, 256, 0, stream>>>(tokw, auxw, wbf);
  k_stats<<<32*32, 256, 0, stream>>>(f0, sums3, 32, SP3, 32, 1024);
  k_finalize<<<1, 64, 0, stream>>>(sums3, g3, b3, scsh3, 32, 1.f/524288.f);
  k_gemm<<<352, 256, 0, stream>>>(f0, wbf, scsh3, out_acc);
  k_final<<<686, 256, 0, stream>>>(out_acc, tokb, auxb, lng, lnb, out);
}

// Round 5
// 1157.321 us; speedup vs baseline: 3.4567x; 1.2338x over previous
//
#include <hip/hip_runtime.h>
#include <hip/hip_bf16.h>

// Geometry (pad=1 convs): conv1/conv2 -> (2,16,128^3), conv3 s2 -> (2,32,64^3)
// patches: 7^3 per batch, M=686, pdim=131072. I/O f32; intermediates bf16.
// Round 4: MFMA conv2 (LDS-resident tile, taps as LDS offsets, no loop barriers).

typedef __hip_bfloat16 bf16;
typedef __attribute__((ext_vector_type(8))) short short8;   // 8 bf16 = 4 VGPR
typedef __attribute__((ext_vector_type(4))) float f32x4;
__device__ __forceinline__ float b2f(bf16 v){ return __bfloat162float(v); }
__device__ __forceinline__ bf16 f2b(float v){ return __float2bfloat16(v); }
__device__ __forceinline__ unsigned short f2bu(float f){   // RNE
  unsigned u = __float_as_uint(f);
  return (unsigned short)((u + 0x7fff + ((u>>16)&1)) >> 16);
}

#define SP12 2097152   // 128^3
#define SP3  262144    // 64^3
#define M_TOT 686
#define TOK_OFF 0
#define AUX_OFF 87808
#define CRD_OFF 109760
#define KSPLIT 32

// ---------------- conv1: (2,1,128^3) -> (2,16,128^3) raw, pad=1 -------------
__global__ __launch_bounds__(256) void k_conv1(const float* __restrict__ x,
                                               const float* __restrict__ w,
                                               bf16* __restrict__ y1){
  __shared__ float wl[432];           // [oc16][27]
  for(int i=threadIdx.x;i<432;i+=256) wl[i]=w[i];
  __syncthreads();
  int t = blockIdx.x*256 + threadIdx.x;
  int xx = t & 127; int yy = (t>>7)&127; int zz = (t>>14)&127; int b = t>>21;
  float acc[16];
#pragma unroll
  for(int o=0;o<16;o++) acc[o]=0.f;
  const float* xb = x + (size_t)b*SP12;
#pragma unroll
  for(int dz=0;dz<3;dz++){
    int iz = zz-1+dz; if((unsigned)iz >= 128u) continue;
#pragma unroll
    for(int dy=0;dy<3;dy++){
      int iy = yy-1+dy; if((unsigned)iy >= 128u) continue;
      const float* row = xb + iz*16384 + iy*128;
#pragma unroll
      for(int dx=0;dx<3;dx++){
        int ix = xx-1+dx; bool ok = (unsigned)ix < 128u;
        float v = row[ok?ix:0]; v = ok? v : 0.f;
        int wi = (dz*3+dy)*3+dx;
#pragma unroll
        for(int o=0;o<16;o++) acc[o] += v*wl[o*27+wi];
      }
    }
  }
  int sp = zz*16384 + yy*128 + xx;
#pragma unroll
  for(int o=0;o<16;o++) y1[(size_t)(b*16+o)*SP12 + sp] = f2b(acc[o]);
}

// ---------------- per-channel sum/sumsq over [b=2][C][SP], 8 bf16/load ------
__device__ __forceinline__ void acc2(unsigned u, float& s, float& q){
  float a = __uint_as_float(u<<16);
  float b = __uint_as_float(u & 0xffff0000u);
  s += a+b; q += a*a+b*b;
}
__global__ __launch_bounds__(256) void k_stats(const bf16* __restrict__ buf,
                                               float* __restrict__ sums,
                                               int C, int SP, int nslab, int chunkV){
  int c = blockIdx.x / nslab; int slab = blockIdx.x % nslab;
  int V = SP >> 3;
  int i0 = slab*chunkV; int i1 = i0+chunkV; if(i1 > V) i1 = V;
  const uint4* p0 = (const uint4*)(buf + (size_t)c*SP);
  const uint4* p1 = (const uint4*)(buf + (size_t)(C+c)*SP);
  float s=0.f, q=0.f;
  for(int i=i0+threadIdx.x; i<i1; i+=256){
    uint4 u = p0[i];
    acc2(u.x,s,q); acc2(u.y,s,q); acc2(u.z,s,q); acc2(u.w,s,q);
    uint4 v = p1[i];
    acc2(v.x,s,q); acc2(v.y,s,q); acc2(v.z,s,q); acc2(v.w,s,q);
  }
  __shared__ float rs[4], rq[4];
#pragma unroll
  for(int off=32;off>0;off>>=1){ s += __shfl_down(s,off); q += __shfl_down(q,off); }
  int lane = threadIdx.x & 63; int wv = threadIdx.x >> 6;
  if(lane==0){ rs[wv]=s; rq[wv]=q; }
  __syncthreads();
  if(threadIdx.x==0){
    atomicAdd(&sums[c],   rs[0]+rs[1]+rs[2]+rs[3]);
    atomicAdd(&sums[C+c], rq[0]+rq[1]+rq[2]+rq[3]);
  }
}

// ------------- scale/shift: scale=g*rsqrt(var+eps), shift=b-mean*scale ------
__global__ void k_finalize(const float* __restrict__ sums, const float* __restrict__ g,
                           const float* __restrict__ bb, float* __restrict__ scsh,
                           int C, float invN){
  int i = threadIdx.x;
  if(i<C){
    float mean = sums[i]*invN;
    float var  = sums[C+i]*invN - mean*mean;
    float sc = g[i]*rsqrtf(var+1e-5f);
    scsh[i]   = sc;
    scsh[C+i] = bb[i] - mean*sc;
  }
}

// ---------------- conv2 (MFMA): bn1+relu on stage, pad=1 --------------------
// Tile 8z x 4y x 16x outputs. LDS input [10][6][18][16ic] bf16 (32B/voxel,
// ic-half 16B blocks XOR-swizzled by (x>>2)&1). W in LDS [oc16][456] with
// k = tap*16+ic, taps 0..26, tap27 = zeros (K padded 432->448 = 14 pairs).
// 4 waves: wave w owns zr {2w,2w+1} x yr{0..3} = 8 M-rows of 16 x.
// A-frag = 1 ds_read_b128 at tap-shifted voxel; C: n=lane&15, m=q*4+reg.
__global__ __launch_bounds__(256) void k_conv2(const bf16* __restrict__ y1,
                                               const float* __restrict__ w,
                                               const float* __restrict__ scsh,
                                               bf16* __restrict__ y2){
  __shared__ unsigned short tile[10*6*18*16];   // 34,560 B
  __shared__ unsigned short Wl[16*456];         // 14,592 B
  __shared__ float s_sc[16], s_sh[16];
  int t = threadIdx.x;
  if(t < 32){ float v = scsh[t]; if(t<16) s_sc[t]=v; else s_sh[t-16]=v; }
  // stage W: Wl[oc][tap*16+ic] = w[(oc*16+ic)*27+tap], tap 27 -> 0
  for(int i=t;i<7168;i+=256){
    int oc = i/448; int k = i - oc*448;
    int tap = k>>4; int ic = k&15;
    float v = (tap<27)? w[(oc*16+ic)*27+tap] : 0.f;
    Wl[oc*456+k] = f2bu(v);
  }
  __syncthreads();                              // s_sc/s_sh ready for staging
  int bx = blockIdx.x;
  int txx = bx&7, tyy=(bx>>3)&31, tzz=(bx>>8)&15, b=bx>>12;
  int x0 = txx*16, y0 = tyy*4, z0 = tzz*8;
  // stage input halo tile with bn1+relu (2 ic per b32 write)
  for(int i=t;i<8640;i+=256){
    int x = i%18; int r1 = i/18; int yy_ = r1%6; int r2 = r1/6;
    int zz_ = r2%10; int icp = r2/10;
    int gx = x0+x-1, gy = y0+yy_-1, gz = z0+zz_-1;
    bool ok = ((unsigned)gx<128u)&&((unsigned)gy<128u)&&((unsigned)gz<128u);
    unsigned pk = 0;
    if(ok){
      int ic0 = icp*2;
      size_t base = (size_t)(b*16+ic0)*SP12 + gz*16384 + gy*128 + gx;
      float v0 = fmaxf(b2f(y1[base])*s_sc[ic0] + s_sh[ic0], 0.f);
      float v1 = fmaxf(b2f(y1[base+SP12])*s_sc[ic0+1] + s_sh[ic0+1], 0.f);
      pk = (unsigned)f2bu(v0) | ((unsigned)f2bu(v1)<<16);
    }
    int h = icp>>2; int sw = (x>>2)&1;
    int wi = ((zz_*6 + yy_)*18 + x)*16 + ((h^sw)*8) + (icp&3)*2;
    *(unsigned*)&tile[wi] = pk;
  }
  __syncthreads();

  int lane = t & 63, wid = t>>6;
  int m = lane & 15, q = lane>>4;
  int qh = q&1, qt = q>>1;
  f32x4 acc[8];
#pragma unroll
  for(int r=0;r<8;r++) acc[r] = (f32x4){0.f,0.f,0.f,0.f};
  const char* tbase = (const char*)tile + wid*6912;   // wave z-base: wid*2 * 6*18*32
  const int woff = m*456;
#pragma unroll
  for(int kp=0;kp<14;kp++){
    short8 bfr = *(const short8*)&Wl[woff + kp*32 + q*8];
    int tap = kp*2 + qt; if(tap>26) tap=26;           // pad tap: zero weights
    int dz = tap/9; int rr = tap - dz*9; int dy = rr/3; int dx = rr - dy*3;
    int xl = m + dx;
    int abyte = ((dz*6 + dy)*18 + xl)*32 + ((qh ^ ((xl>>2)&1))*16);
    const char* ap = tbase + abyte;
#pragma unroll
    for(int r=0;r<8;r++){
      const short8 af = *(const short8*)(ap + ((r>>2)*6 + (r&3))*576);
      acc[r] = __builtin_amdgcn_mfma_f32_16x16x32_bf16(af, bfr, acc[r], 0,0,0);
    }
  }
  // epilogue: n(oc)=lane&15=m, x = x0 + q*4 + reg
#pragma unroll
  for(int r=0;r<8;r++){
    int gz = z0 + wid*2 + (r>>2), gy = y0 + (r&3);
    ushort4 us;
    us.x = f2bu(acc[r][0]); us.y = f2bu(acc[r][1]);
    us.z = f2bu(acc[r][2]); us.w = f2bu(acc[r][3]);
    *(ushort4*)(y2 + (size_t)(b*16+m)*SP12 + gz*16384 + gy*128 + x0 + q*4) = us;
  }
}

// ---------------- conv3 stride2 pad1: bn2+relu on read, ->(2,32,64^3) raw ---
__global__ __launch_bounds__(256) void k_conv3(const bf16* __restrict__ y2,
                                               const float* __restrict__ w,
                                               const float* __restrict__ scsh,
                                               bf16* __restrict__ f0){
  __shared__ float wl[13824];         // [ic16][27][oc32]
  for(int i=threadIdx.x;i<13824;i+=256){
    int oc = i & 31; int k = (i>>5) % 27; int ic = i/864;
    wl[i] = w[(oc*16+ic)*27+k];
  }
  __syncthreads();
  int t = blockIdx.x*256+threadIdx.x;
  int xx = t & 63; int yy = (t>>6)&63; int zz = (t>>12)&63; int b = t>>18;
  float acc[32];
#pragma unroll
  for(int o=0;o<32;o++) acc[o]=0.f;
  for(int ic=0;ic<16;ic++){
    float sc=scsh[ic], sh=scsh[16+ic];
    const bf16* base = y2 + (size_t)(b*16+ic)*SP12;
#pragma unroll
    for(int dz=0;dz<3;dz++){
      int iz = 2*zz-1+dz; if(iz < 0) continue;
#pragma unroll
      for(int dy=0;dy<3;dy++){
        int iy = 2*yy-1+dy; if(iy < 0) continue;
        const bf16* row = base + iz*16384 + iy*128;
        const float* wp = &wl[(ic*27 + (dz*3+dy)*3)*32];
#pragma unroll
        for(int dx=0;dx<3;dx++){
          int ix = 2*xx-1+dx; bool ok = ix >= 0;
          float raw = b2f(row[ok?ix:0]);
          float v = ok ? fmaxf(raw*sc+sh,0.f) : 0.f;
          const float4* w4 = (const float4*)(wp + dx*32);
#pragma unroll
          for(int oq=0;oq<8;oq++){
            float4 wv = w4[oq];
            acc[oq*4+0] += v*wv.x; acc[oq*4+1] += v*wv.y;
            acc[oq*4+2] += v*wv.z; acc[oq*4+3] += v*wv.w;
          }
        }
      }
    }
  }
  int sp = zz*4096 + yy*64 + xx;
#pragma unroll
  for(int o=0;o<32;o++) f0[(size_t)(b*32+o)*SP3 + sp] = f2b(acc[o]);
}

// ---------------- W f32 -> bf16 pre-convert: wb[160][131072] ----------------
__global__ __launch_bounds__(256) void k_cvtw(const float* __restrict__ tokw,
                                              const float* __restrict__ auxw,
                                              unsigned short* __restrict__ wb){
  int i = blockIdx.x*256 + threadIdx.x;
  int n = i >> 15;
  int g = i & 32767;
  const float* src = (n<128)? tokw + (size_t)n*131072 : auxw + (size_t)(n-128)*131072;
  float4 v = *(const float4*)(src + g*4);
  ushort4 o; o.x=f2bu(v.x); o.y=f2bu(v.y); o.z=f2bu(v.z); o.w=f2bu(v.w);
  *(ushort4*)(wb + (size_t)n*131072 + g*4) = o;
}

// ---------------- MFMA projection GEMM: M=686, N=160, K=131072 --------------
__global__ __launch_bounds__(256) void k_gemm(const bf16* __restrict__ f0,
                                              const unsigned short* __restrict__ wb,
                                              const float* __restrict__ scsh3,
                                              float* __restrict__ out_acc){
  __shared__ unsigned short Al[64*72];
  __shared__ unsigned short Wl[160*72];
  int mblk = blockIdx.x % 11; int ks = blockIdx.x / 11;
  int M0 = mblk*64;
  int c  = ks;
  float sc = scsh3[c], sh = scsh3[32+c];
  int t = threadIdx.x;
  int lane = t & 63; int wid = t >> 6;
  int wm = (wid & 1)*32; int wn = (wid >> 1)*80;
  f32x4 acc[2][5];
#pragma unroll
  for(int i=0;i<2;i++)
#pragma unroll
    for(int j=0;j<5;j++) acc[i][j] = (f32x4){0.f,0.f,0.f,0.f};

  int ky_off0 = (t&7)>>1, half0 = t&1;
  int m_a = t>>3;
  int mg1 = M0 + m_a;       if(mg1>685) mg1=685;
  int mg2 = M0 + m_a + 32;  if(mg2>685) mg2=685;
  int b1 = mg1/343, r1 = mg1%343;
  int b2 = mg2/343, r2 = mg2%343;
  int sp1 = ((r1/49)*8)*4096 + (((r1/7)%7)*8)*64 + (r1%7)*8;
  int sp2 = ((r2/49)*8)*4096 + (((r2/7)%7)*8)*64 + (r2%7)*8;
  const bf16* f0c1 = f0 + (size_t)(b1*32+c)*SP3;
  const bf16* f0c2 = f0 + (size_t)(b2*32+c)*SP3;

  for(int bk=0; bk<64; bk++){
    int kz = bk>>2; int kyb = (bk&3)*4;
    __syncthreads();
#pragma unroll
    for(int p=0;p<5;p++){
      int n = p*32 + (t>>3);
      int koff = (t&7)*8;
      uint4 v = *(const uint4*)(wb + (size_t)n*131072 + ks*4096 + bk*64 + koff);
      *(uint4*)&Wl[n*72 + koff] = v;
    }
    {
      int ky = kyb + ky_off0; int xo = half0*8;
      int ldso = ky_off0*16 + half0*8;
      uint4 u1 = *(const uint4*)(f0c1 + sp1 + kz*4096 + ky*64 + xo);
      uint4 u2 = *(const uint4*)(f0c2 + sp2 + kz*4096 + ky*64 + xo);
      unsigned uu[8]; uu[0]=u1.x; uu[1]=u1.y; uu[2]=u1.z; uu[3]=u1.w;
      uu[4]=u2.x; uu[5]=u2.y; uu[6]=u2.z; uu[7]=u2.w;
      unsigned outw[8];
#pragma unroll
      for(int qq=0;qq<8;qq++){
        float lo = fmaxf(__uint_as_float(uu[qq]<<16)*sc + sh, 0.f);
        float hi = fmaxf(__uint_as_float(uu[qq]&0xffff0000u)*sc + sh, 0.f);
        outw[qq] = (unsigned)f2bu(lo) | ((unsigned)f2bu(hi)<<16);
      }
      uint4 w1; w1.x=outw[0]; w1.y=outw[1]; w1.z=outw[2]; w1.w=outw[3];
      uint4 w2; w2.x=outw[4]; w2.y=outw[5]; w2.z=outw[6]; w2.w=outw[7];
      *(uint4*)&Al[m_a*72 + ldso] = w1;
      *(uint4*)&Al[(m_a+32)*72 + ldso] = w2;
    }
    __syncthreads();
#pragma unroll
    for(int kstep=0;kstep<2;kstep++){
      int ko = kstep*32 + (lane>>4)*8;
      short8 af[2], bfr[5];
#pragma unroll
      for(int mt=0;mt<2;mt++)
        af[mt] = *(const short8*)&Al[(wm + mt*16 + (lane&15))*72 + ko];
#pragma unroll
      for(int nt=0;nt<5;nt++)
        bfr[nt] = *(const short8*)&Wl[(wn + nt*16 + (lane&15))*72 + ko];
#pragma unroll
      for(int mt=0;mt<2;mt++)
#pragma unroll
        for(int nt=0;nt<5;nt++)
          acc[mt][nt] = __builtin_amdgcn_mfma_f32_16x16x32_bf16(af[mt], bfr[nt], acc[mt][nt], 0,0,0);
    }
  }
#pragma unroll
  for(int mt=0;mt<2;mt++){
    int mb = M0 + wm + mt*16 + (lane>>4)*4;
#pragma unroll
    for(int nt=0;nt<5;nt++){
      int n = wn + nt*16 + (lane&15);
#pragma unroll
      for(int reg=0;reg<4;reg++){
        int mm = mb + reg;
        if(mm < M_TOT)
          out_acc[((size_t)ks*M_TOT + mm)*160 + n] = acc[mt][nt][reg];
      }
    }
  }
}

// ------------- reduce split-K, +bias, LN(tokens), coords, write out ---------
__global__ __launch_bounds__(256) void k_final(const float* __restrict__ out_acc,
                                               const float* __restrict__ tok_b,
                                               const float* __restrict__ aux_b,
                                               const float* __restrict__ ln_g,
                                               const float* __restrict__ ln_b,
                                               float* __restrict__ out){
  int m = blockIdx.x;            // 0..685
  int n = threadIdx.x;
  __shared__ float sA[128], sB[128];
  float sum = 0.f;
  if(n < 160){
    for(int ks=0;ks<KSPLIT;ks++) sum += out_acc[((size_t)ks*M_TOT+m)*160 + n];
  }
  float tval = 0.f;
  if(n < 128){
    tval = sum + tok_b[n];
    sA[n] = tval; sB[n] = tval*tval;
  }
  __syncthreads();
  for(int s=64;s>0;s>>=1){
    if(n < s){ sA[n] += sA[n+s]; sB[n] += sB[n+s]; }
    __syncthreads();
  }
  float mean = sA[0]*(1.f/128.f);
  float var  = sB[0]*(1.f/128.f) - mean*mean;
  float rstd = rsqrtf(var + 1e-5f);
  if(n<128){
    out[TOK_OFF + (size_t)m*128 + n] = (tval-mean)*rstd*ln_g[n] + ln_b[n];
  } else if(n<160){
    out[AUX_OFF + (size_t)m*32 + (n-128)] = sum + aux_b[n-128];
  } else if(n<163){
    int j = n-160;
    int pn = m % 343;
    int nz = pn/49, ny=(pn/7)%7, nx=pn%7;
    int g = (j==0)? nz : (j==1)? ny : nx;
    out[CRD_OFF + (size_t)m*3 + j] = (g*8 + 7.5f)*(1.f/63.f);
  }
}

extern "C" void kernel_launch(void* const* d_in, const int* in_sizes, int n_in,
                              void* d_out, int out_size, void* d_ws, size_t ws_size,
                              hipStream_t stream){
  const float* x    = (const float*)d_in[0];
  const float* w1   = (const float*)d_in[1];
  const float* g1   = (const float*)d_in[2];
  const float* b1   = (const float*)d_in[3];
  const float* w2   = (const float*)d_in[4];
  const float* g2   = (const float*)d_in[5];
  const float* b2   = (const float*)d_in[6];
  const float* w3   = (const float*)d_in[7];
  const float* g3   = (const float*)d_in[8];
  const float* b3   = (const float*)d_in[9];
  const float* tokw = (const float*)d_in[10];
  const float* tokb = (const float*)d_in[11];
  const float* auxw = (const float*)d_in[12];
  const float* auxb = (const float*)d_in[13];
  const float* lng  = (const float*)d_in[14];
  const float* lnb  = (const float*)d_in[15];
  float* out = (float*)d_out;

  // ws layout (256 MiB): y1 [0,128Mi), y2 [128Mi,256Mi).
  // After conv2, region0 reused: f0 [0,32Mi), out_acc [32Mi,+14.05MB),
  // Wbf16 [64Mi,+41.9MB). Stats (256 f32) in d_out[0..255].
  char* ws = (char*)d_ws;
  bf16*  y1      = (bf16*)ws;
  bf16*  y2      = (bf16*)(ws + 134217728);
  bf16*  f0      = (bf16*)ws;
  float* out_acc = (float*)(ws + 33554432);
  unsigned short* wbf = (unsigned short*)(ws + 67108864);
  float* stats   = (float*)d_out;
  float* sums1 = stats;        float* sums2 = stats+32;  float* sums3 = stats+64;
  float* scsh1 = stats+128;    float* scsh2 = stats+160; float* scsh3 = stats+192;

  hipMemsetAsync(stats, 0, 512, stream);

  k_conv1<<<16384, 256, 0, stream>>>(x, w1, y1);
  k_stats<<<16*64, 256, 0, stream>>>(y1, sums1, 16, SP12, 64, 4096);
  k_finalize<<<1, 64, 0, stream>>>(sums1, g1, b1, scsh1, 16, 1.f/4194304.f);
  k_conv2<<<8192, 256, 0, stream>>>(y1, w2, scsh1, y2);
  k_stats<<<16*64, 256, 0, stream>>>(y2, sums2, 16, SP12, 64, 4096);
  k_finalize<<<1, 64, 0, stream>>>(sums2, g2, b2, scsh2, 16, 1.f/4194304.f);
  k_conv3<<<2048, 256, 0, stream>>>(y2, w3, scsh2, f0);
  k_cvtw<<<20480, 256, 0, stream>>>(tokw, auxw, wbf);
  k_stats<<<32*32, 256, 0, stream>>>(f0, sums3, 32, SP3, 32, 1024);
  k_finalize<<<1, 64, 0, stream>>>(sums3, g3, b3, scsh3, 32, 1.f/524288.f);
  k_gemm<<<352, 256, 0, stream>>>(f0, wbf, scsh3, out_acc);
  k_final<<<686, 256, 0, stream>>>(out_acc, tokb, auxb, lng, lnb, out);
}

// Round 6
// 860.536 us; speedup vs baseline: 4.6488x; 1.3449x over previous
//
#include <hip/hip_runtime.h>
#include <hip/hip_bf16.h>

// Geometry (pad=1): conv1/conv2 -> (2,16,128^3), conv3 s2 -> (2,32,64^3).
// Round 6: voxel-interleaved layouts y1/y2 = [b][z][y][x][ic16] (32B/voxel),
// MFMA conv3, BN stats fused into conv1/conv2/conv3 (slabbed atomics).
// f0 stays channel-major for the gemm gather. I/O f32, intermediates bf16.

typedef __hip_bfloat16 bf16;
typedef __attribute__((ext_vector_type(8))) short short8;   // 8 bf16 = 4 VGPR
typedef __attribute__((ext_vector_type(4))) float f32x4;
__device__ __forceinline__ float b2f(bf16 v){ return __bfloat162float(v); }
__device__ __forceinline__ bf16 f2b(float v){ return __float2bfloat16(v); }
__device__ __forceinline__ unsigned short f2bu(float f){   // RNE
  unsigned u = __float_as_uint(f);
  return (unsigned short)((u + 0x7fff + ((u>>16)&1)) >> 16);
}

#define SP12 2097152   // 128^3
#define SP3  262144    // 64^3
#define M_TOT 686
#define TOK_OFF 0
#define AUX_OFF 87808
#define CRD_OFF 109760
#define KSPLIT 32
#define NSLAB 32

// ---------------- conv1: (2,1,128^3)->(2,16,128^3) raw interleaved + stats --
__global__ __launch_bounds__(256) void k_conv1(const float* __restrict__ x,
                                               const float* __restrict__ w,
                                               unsigned short* __restrict__ y1u,
                                               float* __restrict__ psum1){
  __shared__ float wl[432];           // [oc16][27]
  __shared__ float red[128];
  int t = threadIdx.x;
  for(int i=t;i<432;i+=256) wl[i]=w[i];
  __syncthreads();
  int tt = blockIdx.x*256 + t;
  int xx = tt & 127; int yy = (tt>>7)&127; int zz = (tt>>14)&127; int b = tt>>21;
  float acc[16];
#pragma unroll
  for(int o=0;o<16;o++) acc[o]=0.f;
  const float* xb = x + (size_t)b*SP12;
#pragma unroll
  for(int dz=0;dz<3;dz++){
    int iz = zz-1+dz; if((unsigned)iz >= 128u) continue;
#pragma unroll
    for(int dy=0;dy<3;dy++){
      int iy = yy-1+dy; if((unsigned)iy >= 128u) continue;
      const float* row = xb + iz*16384 + iy*128;
#pragma unroll
      for(int dx=0;dx<3;dx++){
        int ix = xx-1+dx; bool ok = (unsigned)ix < 128u;
        float v = row[ok?ix:0]; v = ok? v : 0.f;
        int wi = (dz*3+dy)*3+dx;
#pragma unroll
        for(int o=0;o<16;o++) acc[o] += v*wl[o*27+wi];
      }
    }
  }
  // interleaved write: voxel tt, 16 ch = 32 B
  unsigned pk[8];
#pragma unroll
  for(int j=0;j<8;j++) pk[j] = (unsigned)f2bu(acc[2*j]) | ((unsigned)f2bu(acc[2*j+1])<<16);
  uint4 u0; u0.x=pk[0]; u0.y=pk[1]; u0.z=pk[2]; u0.w=pk[3];
  uint4 u1; u1.x=pk[4]; u1.y=pk[5]; u1.z=pk[6]; u1.w=pk[7];
  *(uint4*)(y1u + (size_t)tt*16)     = u0;
  *(uint4*)(y1u + (size_t)tt*16 + 8) = u1;
  // fused BN1 stats (raw fp32 acc)
  int lane = t & 63, wid = t>>6;
#pragma unroll
  for(int c=0;c<16;c++){
    float sv = acc[c], qv = acc[c]*acc[c];
#pragma unroll
    for(int off=32;off>0;off>>=1){ sv += __shfl_down(sv,off); qv += __shfl_down(qv,off); }
    if(lane==0){ red[wid*32+c]=sv; red[wid*32+16+c]=qv; }
  }
  __syncthreads();
  if(t<32){
    float tot = red[t]+red[32+t]+red[64+t]+red[96+t];
    atomicAdd(&psum1[(blockIdx.x & (NSLAB-1))*64 + t], tot);
  }
}

// ------------- scale/shift from slabbed sums --------------------------------
__global__ void k_finalize(const float* __restrict__ psum, const float* __restrict__ g,
                           const float* __restrict__ bb, float* __restrict__ scsh,
                           int C, float invN){
  int i = threadIdx.x;
  if(i<C){
    float s=0.f, q=0.f;
    for(int sl=0; sl<NSLAB; sl++){ s += psum[sl*64+i]; q += psum[sl*64+C+i]; }
    float mean = s*invN;
    float var  = q*invN - mean*mean;
    float sc = g[i]*rsqrtf(var+1e-5f);
    scsh[i]   = sc;
    scsh[C+i] = bb[i] - mean*sc;
  }
}

// ---------------- conv2 (MFMA): interleaved in/out, bn1+relu on stage -------
// Tile 8z x 4y x 16x. LDS tile [10][6][18][16ic], halves swizzled by (x>>2)&1.
// W LDS [oc16][456], k = tap*16+ic, tap27 = zeros. Fused BN2 stats.
__global__ __launch_bounds__(256) void k_conv2(const unsigned short* __restrict__ y1u,
                                               const float* __restrict__ w,
                                               const float* __restrict__ scsh,
                                               unsigned short* __restrict__ y2u,
                                               float* __restrict__ psum2){
  __shared__ unsigned short tile[10*6*18*16];   // 34,560 B
  __shared__ unsigned short Wl[16*456];         // 14,592 B
  __shared__ float s_sc[16], s_sh[16];
  int t = threadIdx.x;
  if(t < 32){ float v = scsh[t]; if(t<16) s_sc[t]=v; else s_sh[t-16]=v; }
  for(int i=t;i<7168;i+=256){
    int oc = i/448; int k = i - oc*448;
    int tap = k>>4; int ic = k&15;
    float v = (tap<27)? w[(oc*16+ic)*27+tap] : 0.f;
    Wl[oc*456+k] = f2bu(v);
  }
  __syncthreads();
  int bx = blockIdx.x;
  int txx = bx&7, tyy=(bx>>3)&31, tzz=(bx>>8)&15, b=bx>>12;
  int x0 = txx*16, y0 = tyy*4, z0 = tzz*8;
  // stage: 1080 voxels x 2 halves; one uint4 (8ch) per item, bn1+relu fused
  for(int i=t;i<2160;i+=256){
    int vox = i>>1, h = i&1;
    int xl_ = vox%18; int r1 = vox/18; int yy_ = r1%6; int zz_ = r1/6;
    int gx = x0+xl_-1, gy = y0+yy_-1, gz = z0+zz_-1;
    bool ok = ((unsigned)gx<128u)&&((unsigned)gy<128u)&&((unsigned)gz<128u);
    uint4 o; o.x=0;o.y=0;o.z=0;o.w=0;
    if(ok){
      uint4 u = *(const uint4*)(y1u + ((size_t)((b<<21)|(gz<<14)|(gy<<7)|gx))*16 + h*8);
      int c0 = h*8;
      unsigned uu[4]; uu[0]=u.x; uu[1]=u.y; uu[2]=u.z; uu[3]=u.w;
      unsigned oo[4];
#pragma unroll
      for(int j=0;j<4;j++){
        float lo = fmaxf(__uint_as_float(uu[j]<<16)        *s_sc[c0+2*j]   + s_sh[c0+2*j],   0.f);
        float hi = fmaxf(__uint_as_float(uu[j]&0xffff0000u)*s_sc[c0+2*j+1] + s_sh[c0+2*j+1], 0.f);
        oo[j] = (unsigned)f2bu(lo) | ((unsigned)f2bu(hi)<<16);
      }
      o.x=oo[0]; o.y=oo[1]; o.z=oo[2]; o.w=oo[3];
    }
    int sw = (xl_>>2)&1;
    *(uint4*)&tile[vox*16 + ((h^sw)*8)] = o;
  }
  __syncthreads();

  int lane = t & 63, wid = t>>6;
  int m = lane & 15, q = lane>>4;
  int qh = q&1, qt = q>>1;
  f32x4 acc[8];
#pragma unroll
  for(int r=0;r<8;r++) acc[r] = (f32x4){0.f,0.f,0.f,0.f};
  const char* tbase = (const char*)tile + wid*6912;   // wid*2 z-planes
  const int woff = m*456;
#pragma unroll
  for(int kp=0;kp<14;kp++){
    short8 bfr = *(const short8*)&Wl[woff + kp*32 + q*8];
    int tap = kp*2 + qt; if(tap>26) tap=26;           // pad tap: zero weights
    int dz = tap/9; int rr = tap - dz*9; int dy = rr/3; int dx = rr - dy*3;
    int xl = m + dx;
    int abyte = ((dz*6 + dy)*18 + xl)*32 + ((qh ^ ((xl>>2)&1))*16);
    const char* ap = tbase + abyte;
#pragma unroll
    for(int r=0;r<8;r++){
      const short8 af = *(const short8*)(ap + ((r>>2)*6 + (r&3))*576);
      acc[r] = __builtin_amdgcn_mfma_f32_16x16x32_bf16(af, bfr, acc[r], 0,0,0);
    }
  }
  // epilogue: oc = m, x = x0 + q*4 + reg; interleaved y2 write + stats
  float s=0.f, qv=0.f;
#pragma unroll
  for(int r=0;r<8;r++){
    int gz = z0 + wid*2 + (r>>2), gy = y0 + (r&3);
    size_t vbase = (size_t)((b<<21)|(gz<<14)|(gy<<7)) + x0 + q*4;
#pragma unroll
    for(int reg=0;reg<4;reg++){
      float v = acc[r][reg];
      s += v; qv += v*v;
      y2u[(vbase+reg)*16 + m] = f2bu(v);
    }
  }
  s  += __shfl_xor(s,16);  s  += __shfl_xor(s,32);
  qv += __shfl_xor(qv,16); qv += __shfl_xor(qv,32);
  __syncthreads();                                    // tile reads done
  float* red = (float*)tile;
  if(lane<16){ red[wid*32+lane]=s; red[wid*32+16+lane]=qv; }
  __syncthreads();
  if(t<32){
    float tot = red[t]+red[32+t]+red[64+t]+red[96+t];
    atomicAdd(&psum2[(blockIdx.x & (NSLAB-1))*64 + t], tot);
  }
}

// ---------------- conv3 (MFMA, stride2): interleaved in, channel-major out --
// Out tile 2z x 4y x 16x. LDS in [5][9][33][16ic] (origin at 2*o-1), W [32][456].
// Fused BN3 stats.
__global__ __launch_bounds__(256) void k_conv3(const unsigned short* __restrict__ y2u,
                                               const float* __restrict__ w,
                                               const float* __restrict__ scsh,
                                               bf16* __restrict__ f0,
                                               float* __restrict__ psum3){
  __shared__ unsigned short tile3[5*9*33*16];   // 47,520 B
  __shared__ unsigned short Wl3[32*456];        // 29,184 B
  __shared__ float s_sc[16], s_sh[16];
  int t = threadIdx.x;
  if(t < 32){ float v = scsh[t]; if(t<16) s_sc[t]=v; else s_sh[t-16]=v; }
  for(int i=t;i<14336;i+=256){
    int oc = i/448; int k = i - oc*448;
    int tap = k>>4; int ic = k&15;
    float v = (tap<27)? w[(oc*16+ic)*27+tap] : 0.f;
    Wl3[oc*456+k] = f2bu(v);
  }
  __syncthreads();
  int bx = blockIdx.x;
  int tx = bx&3, ty=(bx>>2)&15, tz=(bx>>6)&31, b=bx>>11;
  int x0 = tx*16, y0 = ty*4, z0 = tz*2;
  int gx0 = 2*x0-1, gy0 = 2*y0-1, gz0 = 2*z0-1;
  for(int i=t;i<2970;i+=256){
    int vox = i>>1, h = i&1;
    int xl_ = vox%33; int r1 = vox/33; int yy_ = r1%9; int zz_ = r1/9;
    int gx = gx0+xl_, gy = gy0+yy_, gz = gz0+zz_;
    bool ok = (gx>=0)&&(gy>=0)&&(gz>=0);
    uint4 o; o.x=0;o.y=0;o.z=0;o.w=0;
    if(ok){
      uint4 u = *(const uint4*)(y2u + ((size_t)((b<<21)|(gz<<14)|(gy<<7)|gx))*16 + h*8);
      int c0 = h*8;
      unsigned uu[4]; uu[0]=u.x; uu[1]=u.y; uu[2]=u.z; uu[3]=u.w;
      unsigned oo[4];
#pragma unroll
      for(int j=0;j<4;j++){
        float lo = fmaxf(__uint_as_float(uu[j]<<16)        *s_sc[c0+2*j]   + s_sh[c0+2*j],   0.f);
        float hi = fmaxf(__uint_as_float(uu[j]&0xffff0000u)*s_sc[c0+2*j+1] + s_sh[c0+2*j+1], 0.f);
        oo[j] = (unsigned)f2bu(lo) | ((unsigned)f2bu(hi)<<16);
      }
      o.x=oo[0]; o.y=oo[1]; o.z=oo[2]; o.w=oo[3];
    }
    int sw = (xl_>>2)&1;
    *(uint4*)&tile3[vox*16 + ((h^sw)*8)] = o;
  }
  __syncthreads();

  int lane = t & 63, wid = t>>6;
  int m = lane & 15, q = lane>>4;
  int qh = q&1, qt = q>>1;
  f32x4 acc[2][2];                                    // [row][oct]
#pragma unroll
  for(int r=0;r<2;r++){ acc[r][0]=(f32x4){0,0,0,0}; acc[r][1]=(f32x4){0,0,0,0}; }
#pragma unroll
  for(int kp=0;kp<14;kp++){
    short8 bf0 = *(const short8*)&Wl3[ m     *456 + kp*32 + q*8];
    short8 bf1 = *(const short8*)&Wl3[(16+m)*456 + kp*32 + q*8];
    int tap = kp*2 + qt; if(tap>26) tap=26;
    int dz = tap/9; int rr = tap - dz*9; int dy = rr/3; int dx = rr - dy*3;
    int xl = 2*m + dx;
    int hb = (qh ^ ((xl>>2)&1))*16;
#pragma unroll
    for(int rl=0;rl<2;rl++){
      int row = wid*2 + rl;
      int tz_ = 2*(row>>2) + dz;
      int ty_ = 2*(row&3) + dy;
      const short8 af = *(const short8*)((const char*)tile3 + ((tz_*9+ty_)*33 + xl)*32 + hb);
      acc[rl][0] = __builtin_amdgcn_mfma_f32_16x16x32_bf16(af, bf0, acc[rl][0], 0,0,0);
      acc[rl][1] = __builtin_amdgcn_mfma_f32_16x16x32_bf16(af, bf1, acc[rl][1], 0,0,0);
    }
  }
  // epilogue: oc = oct*16 + m, x = x0+q*4+reg; f0 channel-major + stats
  float s0=0.f,q0=0.f,s1=0.f,q1=0.f;
#pragma unroll
  for(int rl=0;rl<2;rl++){
    int row = wid*2 + rl;
    int oz = z0 + (row>>2), oy = y0 + (row&3);
    size_t sp = (size_t)oz*4096 + oy*64 + x0 + q*4;
#pragma unroll
    for(int oct=0;oct<2;oct++){
      int oc = oct*16 + m;
      bf16* dst = f0 + (size_t)(b*32+oc)*SP3 + sp;
#pragma unroll
      for(int reg=0;reg<4;reg++){
        float v = acc[rl][oct][reg];
        if(oct==0){ s0 += v; q0 += v*v; } else { s1 += v; q1 += v*v; }
        dst[reg] = f2b(v);
      }
    }
  }
  s0 += __shfl_xor(s0,16); s0 += __shfl_xor(s0,32);
  q0 += __shfl_xor(q0,16); q0 += __shfl_xor(q0,32);
  s1 += __shfl_xor(s1,16); s1 += __shfl_xor(s1,32);
  q1 += __shfl_xor(q1,16); q1 += __shfl_xor(q1,32);
  __syncthreads();
  float* red = (float*)tile3;
  if(lane<16){
    red[wid*64+lane]    = s0; red[wid*64+16+lane] = s1;
    red[wid*64+32+lane] = q0; red[wid*64+48+lane] = q1;
  }
  __syncthreads();
  if(t<64){
    float tot = red[t]+red[64+t]+red[128+t]+red[192+t];
    atomicAdd(&psum3[(blockIdx.x & (NSLAB-1))*64 + t], tot);
  }
}

// ---------------- W f32 -> bf16 pre-convert: wb[160][131072] ----------------
__global__ __launch_bounds__(256) void k_cvtw(const float* __restrict__ tokw,
                                              const float* __restrict__ auxw,
                                              unsigned short* __restrict__ wb){
  int i = blockIdx.x*256 + threadIdx.x;
  int n = i >> 15;
  int g = i & 32767;
  const float* src = (n<128)? tokw + (size_t)n*131072 : auxw + (size_t)(n-128)*131072;
  float4 v = *(const float4*)(src + g*4);
  ushort4 o; o.x=f2bu(v.x); o.y=f2bu(v.y); o.z=f2bu(v.z); o.w=f2bu(v.w);
  *(ushort4*)(wb + (size_t)n*131072 + g*4) = o;
}

// ---------------- MFMA projection GEMM: M=686, N=160, K=131072 --------------
__global__ __launch_bounds__(256) void k_gemm(const bf16* __restrict__ f0,
                                              const unsigned short* __restrict__ wb,
                                              const float* __restrict__ scsh3,
                                              float* __restrict__ out_acc){
  __shared__ unsigned short Al[64*72];
  __shared__ unsigned short Wl[160*72];
  int mblk = blockIdx.x % 11; int ks = blockIdx.x / 11;
  int M0 = mblk*64;
  int c  = ks;
  float sc = scsh3[c], sh = scsh3[32+c];
  int t = threadIdx.x;
  int lane = t & 63; int wid = t >> 6;
  int wm = (wid & 1)*32; int wn = (wid >> 1)*80;
  f32x4 acc[2][5];
#pragma unroll
  for(int i=0;i<2;i++)
#pragma unroll
    for(int j=0;j<5;j++) acc[i][j] = (f32x4){0.f,0.f,0.f,0.f};

  int ky_off0 = (t&7)>>1, half0 = t&1;
  int m_a = t>>3;
  int mg1 = M0 + m_a;       if(mg1>685) mg1=685;
  int mg2 = M0 + m_a + 32;  if(mg2>685) mg2=685;
  int b1 = mg1/343, r1 = mg1%343;
  int b2 = mg2/343, r2 = mg2%343;
  int sp1 = ((r1/49)*8)*4096 + (((r1/7)%7)*8)*64 + (r1%7)*8;
  int sp2 = ((r2/49)*8)*4096 + (((r2/7)%7)*8)*64 + (r2%7)*8;
  const bf16* f0c1 = f0 + (size_t)(b1*32+c)*SP3;
  const bf16* f0c2 = f0 + (size_t)(b2*32+c)*SP3;

  for(int bk=0; bk<64; bk++){
    int kz = bk>>2; int kyb = (bk&3)*4;
    __syncthreads();
#pragma unroll
    for(int p=0;p<5;p++){
      int n = p*32 + (t>>3);
      int koff = (t&7)*8;
      uint4 v = *(const uint4*)(wb + (size_t)n*131072 + ks*4096 + bk*64 + koff);
      *(uint4*)&Wl[n*72 + koff] = v;
    }
    {
      int ky = kyb + ky_off0; int xo = half0*8;
      int ldso = ky_off0*16 + half0*8;
      uint4 u1 = *(const uint4*)(f0c1 + sp1 + kz*4096 + ky*64 + xo);
      uint4 u2 = *(const uint4*)(f0c2 + sp2 + kz*4096 + ky*64 + xo);
      unsigned uu[8]; uu[0]=u1.x; uu[1]=u1.y; uu[2]=u1.z; uu[3]=u1.w;
      uu[4]=u2.x; uu[5]=u2.y; uu[6]=u2.z; uu[7]=u2.w;
      unsigned outw[8];
#pragma unroll
      for(int qq=0;qq<8;qq++){
        float lo = fmaxf(__uint_as_float(uu[qq]<<16)*sc + sh, 0.f);
        float hi = fmaxf(__uint_as_float(uu[qq]&0xffff0000u)*sc + sh, 0.f);
        outw[qq] = (unsigned)f2bu(lo) | ((unsigned)f2bu(hi)<<16);
      }
      uint4 w1; w1.x=outw[0]; w1.y=outw[1]; w1.z=outw[2]; w1.w=outw[3];
      uint4 w2; w2.x=outw[4]; w2.y=outw[5]; w2.z=outw[6]; w2.w=outw[7];
      *(uint4*)&Al[m_a*72 + ldso] = w1;
      *(uint4*)&Al[(m_a+32)*72 + ldso] = w2;
    }
    __syncthreads();
#pragma unroll
    for(int kstep=0;kstep<2;kstep++){
      int ko = kstep*32 + (lane>>4)*8;
      short8 af[2], bfr[5];
#pragma unroll
      for(int mt=0;mt<2;mt++)
        af[mt] = *(const short8*)&Al[(wm + mt*16 + (lane&15))*72 + ko];
#pragma unroll
      for(int nt=0;nt<5;nt++)
        bfr[nt] = *(const short8*)&Wl[(wn + nt*16 + (lane&15))*72 + ko];
#pragma unroll
      for(int mt=0;mt<2;mt++)
#pragma unroll
        for(int nt=0;nt<5;nt++)
          acc[mt][nt] = __builtin_amdgcn_mfma_f32_16x16x32_bf16(af[mt], bfr[nt], acc[mt][nt], 0,0,0);
    }
  }
#pragma unroll
  for(int mt=0;mt<2;mt++){
    int mb = M0 + wm + mt*16 + (lane>>4)*4;
#pragma unroll
    for(int nt=0;nt<5;nt++){
      int n = wn + nt*16 + (lane&15);
#pragma unroll
      for(int reg=0;reg<4;reg++){
        int mm = mb + reg;
        if(mm < M_TOT)
          out_acc[((size_t)ks*M_TOT + mm)*160 + n] = acc[mt][nt][reg];
      }
    }
  }
}

// ------------- reduce split-K, +bias, LN(tokens), coords, write out ---------
__global__ __launch_bounds__(256) void k_final(const float* __restrict__ out_acc,
                                               const float* __restrict__ tok_b,
                                               const float* __restrict__ aux_b,
                                               const float* __restrict__ ln_g,
                                               const float* __restrict__ ln_b,
                                               float* __restrict__ out){
  int m = blockIdx.x;            // 0..685
  int n = threadIdx.x;
  __shared__ float sA[128], sB[128];
  float sum = 0.f;
  if(n < 160){
    for(int ks=0;ks<KSPLIT;ks++) sum += out_acc[((size_t)ks*M_TOT+m)*160 + n];
  }
  float tval = 0.f;
  if(n < 128){
    tval = sum + tok_b[n];
    sA[n] = tval; sB[n] = tval*tval;
  }
  __syncthreads();
  for(int s=64;s>0;s>>=1){
    if(n < s){ sA[n] += sA[n+s]; sB[n] += sB[n+s]; }
    __syncthreads();
  }
  float mean = sA[0]*(1.f/128.f);
  float var  = sB[0]*(1.f/128.f) - mean*mean;
  float rstd = rsqrtf(var + 1e-5f);
  if(n<128){
    out[TOK_OFF + (size_t)m*128 + n] = (tval-mean)*rstd*ln_g[n] + ln_b[n];
  } else if(n<160){
    out[AUX_OFF + (size_t)m*32 + (n-128)] = sum + aux_b[n-128];
  } else if(n<163){
    int j = n-160;
    int pn = m % 343;
    int nz = pn/49, ny=(pn/7)%7, nx=pn%7;
    int g = (j==0)? nz : (j==1)? ny : nx;
    out[CRD_OFF + (size_t)m*3 + j] = (g*8 + 7.5f)*(1.f/63.f);
  }
}

extern "C" void kernel_launch(void* const* d_in, const int* in_sizes, int n_in,
                              void* d_out, int out_size, void* d_ws, size_t ws_size,
                              hipStream_t stream){
  const float* x    = (const float*)d_in[0];
  const float* w1   = (const float*)d_in[1];
  const float* g1   = (const float*)d_in[2];
  const float* b1   = (const float*)d_in[3];
  const float* w2   = (const float*)d_in[4];
  const float* g2   = (const float*)d_in[5];
  const float* b2   = (const float*)d_in[6];
  const float* w3   = (const float*)d_in[7];
  const float* g3   = (const float*)d_in[8];
  const float* b3   = (const float*)d_in[9];
  const float* tokw = (const float*)d_in[10];
  const float* tokb = (const float*)d_in[11];
  const float* auxw = (const float*)d_in[12];
  const float* auxb = (const float*)d_in[13];
  const float* lng  = (const float*)d_in[14];
  const float* lnb  = (const float*)d_in[15];
  float* out = (float*)d_out;

  // ws (256 MiB): y1 [0,128Mi) interleaved, y2 [128Mi,256Mi) interleaved.
  // After conv2, region0 reused: f0 [0,32Mi) channel-major,
  // out_acc [32Mi,+14.05MB), wbf [64Mi,+41.9MB).
  // Stats scratch in d_out: psum1/2/3 (32 slabs x 64) + scsh1/2/3.
  char* ws = (char*)d_ws;
  unsigned short* y1u = (unsigned short*)ws;
  unsigned short* y2u = (unsigned short*)(ws + 134217728);
  bf16*  f0      = (bf16*)ws;
  float* out_acc = (float*)(ws + 33554432);
  unsigned short* wbf = (unsigned short*)(ws + 67108864);
  float* stats   = (float*)d_out;
  float* psum1 = stats;        float* psum2 = stats+2048; float* psum3 = stats+4096;
  float* scsh1 = stats+6144;   float* scsh2 = stats+6208; float* scsh3 = stats+6272;

  hipMemsetAsync(stats, 0, 6144*sizeof(float), stream);

  k_conv1<<<16384, 256, 0, stream>>>(x, w1, y1u, psum1);
  k_finalize<<<1, 64, 0, stream>>>(psum1, g1, b1, scsh1, 16, 1.f/4194304.f);
  k_conv2<<<8192, 256, 0, stream>>>(y1u, w2, scsh1, y2u, psum2);
  k_finalize<<<1, 64, 0, stream>>>(psum2, g2, b2, scsh2, 16, 1.f/4194304.f);
  k_conv3<<<4096, 256, 0, stream>>>(y2u, w3, scsh2, f0, psum3);
  k_finalize<<<1, 64, 0, stream>>>(psum3, g3, b3, scsh3, 32, 1.f/524288.f);
  k_cvtw<<<20480, 256, 0, stream>>>(tokw, auxw, wbf);
  k_gemm<<<352, 256, 0, stream>>>(f0, wbf, scsh3, out_acc);
  k_final<<<686, 256, 0, stream>>>(out_acc, tokb, auxb, lng, lnb, out);
}